// Round 1
// baseline (3208.128 us; speedup 1.0000x reference)
//
#include <hip/hip_runtime.h>
#include <cmath>

#define NA 10000
#define NE 160000
#define KC 64
#define NEL 10
#define NBR 8
#define NGR 16
#define ECH 16

#define C0 0.28209479177387814f
#define C1 0.4886025119029199f
#define C2 1.0925484305920792f
#define C3 0.31539156525252005f
#define C4 0.5462742152960396f
#define C5 0.5900435899266435f
#define C6 2.890611442640554f
#define C7 0.4570457994644658f
#define C8 0.3731763325901154f
#define C9 1.445305721320277f
#define SQ4PI 3.5449077018110318f
#define PREF 0.6324555320336759f   // sqrt(2/5)
#define PI_F 3.14159265358979323846f

__device__ __forceinline__ float sigmoidf_(float x){ return 1.0f/(1.0f+expf(-x)); }

// ---------------- edge geometry ----------------
__global__ void edge_geom_k(const float* __restrict__ pos, const float* __restrict__ shifts,
                            const int* __restrict__ eidx,
                            float* __restrict__ vecb, float* __restrict__ rbuf,
                            float* __restrict__ shb, float* __restrict__ rbb){
  int e = blockIdx.x*blockDim.x + threadIdx.x;
  if (e >= NE) return;
  int sn = eidx[e], rc = eidx[NE+e];
  float vx = pos[rc*3+0]-pos[sn*3+0]+shifts[e*3+0];
  float vy = pos[rc*3+1]-pos[sn*3+1]+shifts[e*3+1];
  float vz = pos[rc*3+2]-pos[sn*3+2]+shifts[e*3+2];
  float r = sqrtf(vx*vx+vy*vy+vz*vz+1e-12f);
  vecb[e*3+0]=vx; vecb[e*3+1]=vy; vecb[e*3+2]=vz; rbuf[e]=r;
  float inv = 1.0f/r; float x=vx*inv,y=vy*inv,z=vz*inv;
  float x2=x*x,y2=y*y,z2=z*z;
  float Y[16];
  Y[0]=C0; Y[1]=C1*y; Y[2]=C1*z; Y[3]=C1*x;
  Y[4]=C2*x*y; Y[5]=C2*y*z; Y[6]=C3*(3.f*z2-1.f); Y[7]=C2*x*z; Y[8]=C4*(x2-y2);
  Y[9]=C5*y*(3.f*x2-y2); Y[10]=C6*x*y*z; Y[11]=C7*y*(5.f*z2-1.f);
  Y[12]=C8*z*(5.f*z2-3.f); Y[13]=C7*x*(5.f*z2-1.f); Y[14]=C9*z*(x2-y2);
  Y[15]=C5*x*(x2-3.f*y2);
  #pragma unroll
  for (int m=0;m<16;m++) shb[e*16+m] = Y[m]*SQ4PI;
  float u = r*0.2f;
  float fc = 0.f;
  if (u < 1.0f){ float u2=u*u,u4=u2*u2,u5=u4*u,u6=u5*u,u7=u6*u; fc = 1.f-21.f*u5+35.f*u6-15.f*u7; }
  #pragma unroll
  for (int b=0;b<NBR;b++){
    float a = (float)(b+1)*PI_F*0.2f;
    rbb[e*NBR+b] = PREF*sinf(a*r)*inv*fc;
  }
}

// ---------------- embed: h0 = attrs @ embed_W ----------------
__global__ void embed_k(const float* __restrict__ attrs, const float* __restrict__ W, float* __restrict__ h0){
  int idx = blockIdx.x*blockDim.x+threadIdx.x;
  if (idx >= NA*KC) return;
  int n = idx>>6, k = idx&63;
  float s=0;
  #pragma unroll
  for (int j=0;j<NEL;j++) s += attrs[n*NEL+j]*W[j*KC+k];
  h0[idx]=s;
}

// hu[n][k] = sum_c h[n][c]*lin[c][k]
__global__ void hu_k(const float* __restrict__ h, const float* __restrict__ lin, float* __restrict__ out){
  int idx = blockIdx.x*blockDim.x+threadIdx.x;
  if (idx >= NA*KC) return;
  int n = idx>>6, k = idx&63;
  float s=0;
  for (int c=0;c<KC;c++) s += h[n*KC+c]*lin[c*KC+k];
  out[idx]=s;
}

// gh[n][k] = sum_c ghu[n][c]*lin[k][c]   (transpose)
__global__ void ghu_to_gh_k(const float* __restrict__ g, const float* __restrict__ lin, float* __restrict__ out){
  int idx = blockIdx.x*blockDim.x+threadIdx.x;
  if (idx >= NA*KC) return;
  int n = idx>>6, k = idx&63;
  float s=0;
  for (int c=0;c<KC;c++) s += g[n*KC+c]*lin[k*KC+c];
  out[idx]=s;
}

// ---------------- CSR build ----------------
__global__ void count_k(const int* __restrict__ eidx, int* __restrict__ cnt){
  int e = blockIdx.x*blockDim.x+threadIdx.x;
  if (e<NE) atomicAdd(&cnt[eidx[NE+e]], 1);
}
__global__ void scan_k(const int* __restrict__ cnt, int* __restrict__ rs, int* __restrict__ fill){
  __shared__ int part[256];
  int t = threadIdx.x;
  const int PER = (NA + 255)/256;
  int base = t*PER;
  int s = 0;
  for (int j=0;j<PER;j++){ int i=base+j; if (i<NA) s += cnt[i]; }
  part[t] = s; __syncthreads();
  for (int off=1; off<256; off<<=1){
    int v = (t>=off) ? part[t-off] : 0;
    __syncthreads();
    part[t] += v;
    __syncthreads();
  }
  int run = (t==0) ? 0 : part[t-1];
  for (int j=0;j<PER;j++){ int i=base+j; if (i<NA){ rs[i]=run; fill[i]=run; run += cnt[i]; } }
  if (t==255) rs[NA]=run;
}
__global__ void place_k(const int* __restrict__ eidx, int* __restrict__ fill, int* __restrict__ perm){
  int e = blockIdx.x*blockDim.x+threadIdx.x;
  if (e>=NE) return;
  int r = eidx[NE+e];
  int p = atomicAdd(&fill[r],1);
  perm[p]=e;
}

// ---------------- Wr2 transpose ----------------
__global__ void wr2t_k(const float* __restrict__ Wr2, float* __restrict__ Wr2T){
  int idx = blockIdx.x*blockDim.x+threadIdx.x;
  if (idx >= 2*KC*1024) return;
  int l = idx>>16;
  int rem = idx & 65535;
  int c = rem>>10, o = rem&1023;
  Wr2T[l*65536 + o*64 + c] = Wr2[idx];
}

// ---------------- forward: A accumulation per node ----------------
__global__ __launch_bounds__(256) void fwd_A_k(const int* __restrict__ rs, const int* __restrict__ perm,
    const int* __restrict__ eidx, const float* __restrict__ shb, const float* __restrict__ rbb,
    const float* __restrict__ hu, const float* __restrict__ Wr1, const float* __restrict__ Wr2,
    float* __restrict__ A){
  int n = blockIdx.x, t = threadIdx.x;
  int e0 = rs[n], e1 = rs[n+1];
  __shared__ float s_sh[ECH][16];
  __shared__ float s_rb[ECH][NBR];
  __shared__ float s_hu[ECH][KC];
  __shared__ float s_s[KC][20];
  __shared__ int s_snd[ECH];
  int k = t>>2, mb=(t&3)*4;
  float acc0=0,acc1=0,acc2=0,acc3=0;
  for (int ce=e0; ce<e1; ce+=ECH){
    __syncthreads();
    int ne = min(ECH, e1-ce);
    if (t<ECH) s_snd[t] = (t<ne) ? eidx[perm[ce+t]] : 0;
    { int le=t>>4, m=t&15; s_sh[le][m] = (le<ne) ? shb[perm[ce+le]*16+m] : 0.f; }
    if (t < ECH*NBR){ int le=t>>3, b=t&7; s_rb[le][b] = (le<ne) ? rbb[perm[ce+le]*NBR+b] : 0.f; }
    __syncthreads();
    #pragma unroll
    for (int q=0;q<4;q++){
      int idx=q*256+t; int le=idx>>6, c=idx&63;
      s_hu[le][c] = (le<ne) ? hu[s_snd[le]*KC+c] : 0.f;
      float tt=0;
      #pragma unroll
      for (int b=0;b<NBR;b++) tt += s_rb[le][b]*Wr1[b*KC+c];
      s_s[c][le] = (le<ne) ? tt*sigmoidf_(tt) : 0.f;
    }
    __syncthreads();
    float Rl[ECH*4];
    #pragma unroll
    for (int i=0;i<ECH*4;i++) Rl[i]=0.f;
    for (int c=0;c<KC;c++){
      const float4 w = *(const float4*)(Wr2 + (c<<10) + (t<<2));
      float4 sa = *(const float4*)&s_s[c][0];
      float4 sb = *(const float4*)&s_s[c][4];
      float4 sc = *(const float4*)&s_s[c][8];
      float4 sd = *(const float4*)&s_s[c][12];
      float se[16] = {sa.x,sa.y,sa.z,sa.w, sb.x,sb.y,sb.z,sb.w, sc.x,sc.y,sc.z,sc.w, sd.x,sd.y,sd.z,sd.w};
      #pragma unroll
      for (int le=0;le<ECH;le++){
        Rl[le*4+0]+=se[le]*w.x; Rl[le*4+1]+=se[le]*w.y; Rl[le*4+2]+=se[le]*w.z; Rl[le*4+3]+=se[le]*w.w;
      }
    }
    #pragma unroll
    for (int le=0;le<ECH;le++){
      float huv = s_hu[le][k];
      acc0 += Rl[le*4+0]*s_sh[le][mb+0]*huv;
      acc1 += Rl[le*4+1]*s_sh[le][mb+1]*huv;
      acc2 += Rl[le*4+2]*s_sh[le][mb+2]*huv;
      acc3 += Rl[le*4+3]*s_sh[le][mb+3]*huv;
    }
  }
  float4 o;
  const float inv16 = 1.f/16.f;
  o.x=acc0*inv16; o.y=acc1*inv16; o.z=acc2*inv16; o.w=acc3*inv16;
  *(float4*)(A + n*1024 + (t<<2)) = o;
}

// ---------------- product basis fwd ----------------
__global__ void pb_fwd_k(const float* __restrict__ A, const float* __restrict__ Wp, float* __restrict__ h){
  int idx = blockIdx.x*blockDim.x+threadIdx.x;
  if (idx>=NA*KC) return;
  int k = idx&63;
  const float* a = A + idx*16;
  float v[16];
  #pragma unroll
  for (int m=0;m<16;m++) v[m]=a[m];
  float p0 = v[0]*v[0];
  float p1 = v[1]*v[1]+v[2]*v[2]+v[3]*v[3];
  float p2 = v[4]*v[4]+v[5]*v[5]+v[6]*v[6]+v[7]*v[7]+v[8]*v[8];
  float p3 = 0.f;
  #pragma unroll
  for (int m=9;m<16;m++) p3 += v[m]*v[m];
  float P = p0+p1+p2+p3;
  const float* wp = Wp + k*6;
  h[idx] = v[0]*wp[0] + p0*wp[1] + p1*wp[2] + p2*wp[3] + p3*wp[4] + v[0]*P*wp[5];
}

// ---------------- product basis bwd ----------------
__global__ void pb_bwd_k(const float* __restrict__ A, const float* __restrict__ Wp,
                         const float* __restrict__ gh, const float* __restrict__ Wread,
                         int useW, float* __restrict__ gA){
  int idx = blockIdx.x*blockDim.x+threadIdx.x;
  if (idx>=NA*KC) return;
  int k = idx&63;
  const float* a = A + idx*16;
  float v[16];
  #pragma unroll
  for (int m=0;m<16;m++) v[m]=a[m];
  float p0 = v[0]*v[0];
  float p1 = v[1]*v[1]+v[2]*v[2]+v[3]*v[3];
  float p2 = v[4]*v[4]+v[5]*v[5]+v[6]*v[6]+v[7]*v[7]+v[8]*v[8];
  float p3 = 0.f;
  #pragma unroll
  for (int m=9;m<16;m++) p3 += v[m]*v[m];
  float P = p0+p1+p2+p3;
  float g = useW ? Wread[k] : gh[idx];
  const float* wp = Wp + k*6;
  float w5a0 = wp[5]*v[0];
  float out[16];
  #pragma unroll
  for (int m=0;m<16;m++){
    int l = (m==0)?0:(m<4)?1:(m<9)?2:3;
    float r = 2.f*v[m]*(wp[1+l] + w5a0);
    if (m==0) r += wp[0] + wp[5]*P;
    out[m] = g*r;
  }
  float* d = gA + idx*16;
  #pragma unroll
  for (int m=0;m<16;m++) d[m]=out[m];
}

// ---------------- backward edge kernel ----------------
__global__ __launch_bounds__(256) void bwd_edge_k(const int* __restrict__ eidx,
    const float* __restrict__ shb, const float* __restrict__ rbb,
    const float* __restrict__ vecb, const float* __restrict__ rbuf,
    const float* __restrict__ hu, const float* __restrict__ Wr1,
    const float* __restrict__ Wr2, const float* __restrict__ Wr2T,
    const float* __restrict__ gA, float* __restrict__ ghu, int do_ghu,
    float* __restrict__ gpos){
  int t = threadIdx.x;
  int eb = blockIdx.x*ECH;
  __shared__ float s_sh[ECH][16];
  __shared__ float s_rb[ECH][NBR];
  __shared__ float s_hu[ECH][KC];
  __shared__ float s_s[KC][20];
  __shared__ float s_gRt[ECH][256];
  __shared__ float s_gshp[4][ECH][16];
  __shared__ float s_gt[ECH][KC];
  __shared__ float s_grb[ECH][NBR];
  __shared__ int s_snd[ECH], s_rcv[ECH];
  int k=t>>2, mb=(t&3)*4, wv=t>>6, lane=t&63;
  const float inv16 = 1.f/16.f;

  if (t<ECH){ s_snd[t]=eidx[eb+t]; s_rcv[t]=eidx[NE+eb+t]; }
  { int le=t>>4, m=t&15; s_sh[le][m]=shb[(eb+le)*16+m]; }
  if (t<ECH*NBR){ int le=t>>3, b=t&7; s_rb[le][b]=rbb[(eb+le)*NBR+b]; }
  __syncthreads();
  #pragma unroll
  for (int q=0;q<4;q++){
    int idx=q*256+t; int le=idx>>6, c=idx&63;
    s_hu[le][c]=hu[s_snd[le]*KC+c];
    float tt=0;
    #pragma unroll
    for (int b=0;b<NBR;b++) tt += s_rb[le][b]*Wr1[b*KC+c];
    s_s[c][le]=tt*sigmoidf_(tt);
  }
  __syncthreads();

  // recompute R (fwd GEMM)
  float Rl[ECH*4];
  #pragma unroll
  for (int i=0;i<ECH*4;i++) Rl[i]=0.f;
  for (int c=0;c<KC;c++){
    const float4 w = *(const float4*)(Wr2 + (c<<10) + (t<<2));
    float4 sa = *(const float4*)&s_s[c][0];
    float4 sb = *(const float4*)&s_s[c][4];
    float4 sc = *(const float4*)&s_s[c][8];
    float4 sd = *(const float4*)&s_s[c][12];
    float se[16] = {sa.x,sa.y,sa.z,sa.w, sb.x,sb.y,sb.z,sb.w, sc.x,sc.y,sc.z,sc.w, sd.x,sd.y,sd.z,sd.w};
    #pragma unroll
    for (int le=0;le<ECH;le++){
      Rl[le*4+0]+=se[le]*w.x; Rl[le*4+1]+=se[le]*w.y; Rl[le*4+2]+=se[le]*w.z; Rl[le*4+3]+=se[le]*w.w;
    }
  }

  // per-edge: g_hu (atomic), g_sh partials
  #pragma unroll
  for (int le=0;le<ECH;le++){
    float4 gm4 = *(const float4*)(gA + s_rcv[le]*1024 + (t<<2));
    float g0=gm4.x*inv16, g1=gm4.y*inv16, g2=gm4.z*inv16, g3=gm4.w*inv16;
    float p0=g0*Rl[le*4+0], p1=g1*Rl[le*4+1], p2=g2*Rl[le*4+2], p3=g3*Rl[le*4+3];
    float sh0=s_sh[le][mb+0], sh1=s_sh[le][mb+1], sh2=s_sh[le][mb+2], sh3=s_sh[le][mb+3];
    float huv = s_hu[le][k];
    if (do_ghu){
      float ch = p0*sh0+p1*sh1+p2*sh2+p3*sh3;
      ch += __shfl_xor(ch,1); ch += __shfl_xor(ch,2);
      if ((t&3)==0) atomicAdd(&ghu[s_snd[le]*KC + k], ch);
    }
    float q0=p0*huv, q1=p1*huv, q2=p2*huv, q3=p3*huv;
    #pragma unroll
    for (int off=4; off<64; off<<=1){
      q0+=__shfl_xor(q0,off); q1+=__shfl_xor(q1,off); q2+=__shfl_xor(q2,off); q3+=__shfl_xor(q3,off);
    }
    if (lane<4){
      s_gshp[wv][le][mb+0]=q0; s_gshp[wv][le][mb+1]=q1; s_gshp[wv][le][mb+2]=q2; s_gshp[wv][le][mb+3]=q3;
    }
  }

  // bwd GEMM: g_s[e][c] = sum_o gR[e][o]*Wr2T[o][c], o-tiled through LDS
  int cg = t&63, grp = t>>6;
  float aq[4] = {0,0,0,0};
  for (int ot=0; ot<4; ot++){
    __syncthreads();
    int o = ot*256 + t;
    int mo = o&15, ko = o>>4;
    #pragma unroll
    for (int le=0;le<ECH;le++){
      s_gRt[le][t] = gA[s_rcv[le]*1024 + o]*inv16 * s_sh[le][mo] * s_hu[le][ko];
    }
    __syncthreads();
    for (int oo=0; oo<256; oo+=4){
      int ob = ot*256+oo;
      float w0=Wr2T[(ob+0)*64+cg], w1=Wr2T[(ob+1)*64+cg], w2=Wr2T[(ob+2)*64+cg], w3=Wr2T[(ob+3)*64+cg];
      #pragma unroll
      for (int q=0;q<4;q++){
        float4 rr = *(const float4*)&s_gRt[grp*4+q][oo];
        aq[q] += rr.x*w0 + rr.y*w1 + rr.z*w2 + rr.w*w3;
      }
    }
  }
  __syncthreads();
  // g_t = g_s * dsilu(t)
  #pragma unroll
  for (int q=0;q<4;q++){
    int le = grp*4+q;
    float tt=0;
    #pragma unroll
    for (int b=0;b<NBR;b++) tt += s_rb[le][b]*Wr1[b*KC+cg];
    float sg = sigmoidf_(tt);
    float ds = sg*(1.f+tt*(1.f-sg));
    s_gt[le][cg] = aq[q]*ds;
  }
  __syncthreads();
  // g_rb
  if (t < ECH*NBR){
    int le=t>>3, b=t&7;
    float s=0;
    for (int c=0;c<KC;c++) s += s_gt[le][c]*Wr1[b*KC+c];
    s_grb[le][b]=s;
  }
  // reduce gsh partials
  { int le=t>>4, m=t&15;
    s_gshp[0][le][m] = s_gshp[0][le][m]+s_gshp[1][le][m]+s_gshp[2][le][m]+s_gshp[3][le][m]; }
  __syncthreads();
  // per-edge geometry backward
  if (t < ECH){
    int le=t; int e=eb+le;
    float r = rbuf[e]; float inv=1.f/r;
    float vx=vecb[e*3+0], vy=vecb[e*3+1], vz=vecb[e*3+2];
    float x=vx*inv, y=vy*inv, z=vz*inv;
    float x2=x*x, y2=y*y, z2=z*z;
    float G[16];
    #pragma unroll
    for (int m=0;m<16;m++) G[m]=s_gshp[0][le][m];
    float gx = C1*G[3] + C2*(y*G[4]+z*G[7]) + 2.f*C4*x*G[8] + 6.f*C5*x*y*G[9]
             + C6*y*z*G[10] + C7*(5.f*z2-1.f)*G[13] + 2.f*C9*x*z*G[14] + 3.f*C5*(x2-y2)*G[15];
    float gy = C1*G[1] + C2*(x*G[4]+z*G[5]) - 2.f*C4*y*G[8] + 3.f*C5*(x2-y2)*G[9]
             + C6*x*z*G[10] + C7*(5.f*z2-1.f)*G[11] - 2.f*C9*y*z*G[14] - 6.f*C5*x*y*G[15];
    float gz = C1*G[2] + C2*(y*G[5]+x*G[7]) + 6.f*C3*z*G[6] + C6*x*y*G[10]
             + 10.f*C7*y*z*G[11] + C8*(15.f*z2-3.f)*G[12] + 10.f*C7*x*z*G[13] + C9*(x2-y2)*G[14];
    gx*=SQ4PI; gy*=SQ4PI; gz*=SQ4PI;
    // radial path
    float gr=0.f;
    float u=r*0.2f;
    if (u<1.f){
      float u2=u*u, u4=u2*u2, u5=u4*u, u6=u5*u, u7=u6*u;
      float fc=1.f-21.f*u5+35.f*u6-15.f*u7;
      float dfc=(-105.f*u4+210.f*u5-105.f*u6)*0.2f;
      #pragma unroll
      for (int b=0;b<NBR;b++){
        float a=(float)(b+1)*PI_F*0.2f;
        float sa=sinf(a*r), ca=cosf(a*r);
        float bes=PREF*sa*inv;
        float dbes=PREF*(a*ca*inv - sa*inv*inv);
        gr += s_grb[le][b]*(dbes*fc + bes*dfc);
      }
    }
    float dot = x*gx+y*gy+z*gz;
    float gvx = (gx - x*dot)*inv + gr*x;
    float gvy = (gy - y*dot)*inv + gr*y;
    float gvz = (gz - z*dot)*inv + gr*z;
    int sn=s_snd[le], rc=s_rcv[le];
    atomicAdd(&gpos[rc*3+0], gvx); atomicAdd(&gpos[rc*3+1], gvy); atomicAdd(&gpos[rc*3+2], gvz);
    atomicAdd(&gpos[sn*3+0], -gvx); atomicAdd(&gpos[sn*3+1], -gvy); atomicAdd(&gpos[sn*3+2], -gvz);
  }
}

// ---------------- energy + forces ----------------
__global__ void energy_k(const float* __restrict__ attrs, const float* __restrict__ ae,
                         const float* __restrict__ h2, const float* __restrict__ Wread,
                         const int* __restrict__ batch, float* __restrict__ out_e){
  int n = blockIdx.x*blockDim.x+threadIdx.x;
  if (n>=NA) return;
  float v=0;
  #pragma unroll
  for (int j=0;j<NEL;j++) v += attrs[n*NEL+j]*ae[j];
  float s=0;
  for (int kk=0;kk<KC;kk++) s += h2[n*KC+kk]*Wread[kk];
  atomicAdd(&out_e[batch[n]], v+s);
}
__global__ void forces_k(const float* __restrict__ gpos, float* __restrict__ out_f){
  int i = blockIdx.x*blockDim.x+threadIdx.x;
  if (i<NA*3) out_f[i] = -gpos[i];
}

extern "C" void kernel_launch(void* const* d_in, const int* in_sizes, int n_in,
                              void* d_out, int out_size, void* d_ws, size_t ws_size,
                              hipStream_t stream){
  const float* pos    = (const float*)d_in[0];
  const float* attrs  = (const float*)d_in[1];
  const float* shifts = (const float*)d_in[2];
  const int*   eidx   = (const int*)d_in[3];
  const int*   batch  = (const int*)d_in[4];
  const float* ae     = (const float*)d_in[6];
  const float* embedW = (const float*)d_in[7];
  const float* Wr1    = (const float*)d_in[8];
  const float* Wr2    = (const float*)d_in[9];
  const float* lin    = (const float*)d_in[10];
  const float* Wp     = (const float*)d_in[11];
  const float* Wread  = (const float*)d_in[12];
  float* out_e = (float*)d_out;
  float* out_f = out_e + NGR;

  char* w = (char*)d_ws;
  auto alloc = [&](size_t nElem)->void*{ void* p = (void*)w; w += ((nElem*4 + 255)/256)*256; return p; };
  float* vecb = (float*)alloc((size_t)3*NE);
  float* rbuf = (float*)alloc((size_t)NE);
  float* shb  = (float*)alloc((size_t)16*NE);
  float* rbb  = (float*)alloc((size_t)8*NE);
  float* h0   = (float*)alloc((size_t)NA*KC);
  float* h1   = (float*)alloc((size_t)NA*KC);
  float* h2   = (float*)alloc((size_t)NA*KC);
  float* hu1  = (float*)alloc((size_t)NA*KC);
  float* hu2  = (float*)alloc((size_t)NA*KC);
  float* gh1  = (float*)alloc((size_t)NA*KC);
  float* ghu2 = (float*)alloc((size_t)NA*KC);
  float* A1   = (float*)alloc((size_t)NA*1024);
  float* A2   = (float*)alloc((size_t)NA*1024);
  float* gA   = (float*)alloc((size_t)NA*1024);
  float* gpos = (float*)alloc((size_t)NA*3);
  float* Wr2T = (float*)alloc((size_t)2*65536);
  int* cnt  = (int*)alloc((size_t)NA);
  int* rsar = (int*)alloc((size_t)NA+1);
  int* fill = (int*)alloc((size_t)NA);
  int* perm = (int*)alloc((size_t)NE);

  hipMemsetAsync(cnt, 0, NA*sizeof(int), stream);
  hipMemsetAsync(gpos, 0, NA*3*sizeof(float), stream);
  hipMemsetAsync(ghu2, 0, NA*KC*sizeof(float), stream);
  hipMemsetAsync(out_e, 0, NGR*sizeof(float), stream);

  wr2t_k<<<(2*KC*1024+255)/256, 256, 0, stream>>>(Wr2, Wr2T);
  edge_geom_k<<<(NE+255)/256, 256, 0, stream>>>(pos, shifts, eidx, vecb, rbuf, shb, rbb);
  embed_k<<<(NA*KC+255)/256, 256, 0, stream>>>(attrs, embedW, h0);
  count_k<<<(NE+255)/256, 256, 0, stream>>>(eidx, cnt);
  scan_k<<<1, 256, 0, stream>>>(cnt, rsar, fill);
  place_k<<<(NE+255)/256, 256, 0, stream>>>(eidx, fill, perm);

  // layer 0
  hu_k<<<(NA*KC+255)/256, 256, 0, stream>>>(h0, lin + 0, hu1);
  fwd_A_k<<<NA, 256, 0, stream>>>(rsar, perm, eidx, shb, rbb, hu1, Wr1 + 0, Wr2 + 0, A1);
  pb_fwd_k<<<(NA*KC+255)/256, 256, 0, stream>>>(A1, Wp + 0, h1);
  // layer 1
  hu_k<<<(NA*KC+255)/256, 256, 0, stream>>>(h1, lin + 4096, hu2);
  fwd_A_k<<<NA, 256, 0, stream>>>(rsar, perm, eidx, shb, rbb, hu2, Wr1 + 512, Wr2 + 65536, A2);
  pb_fwd_k<<<(NA*KC+255)/256, 256, 0, stream>>>(A2, Wp + 384, h2);

  energy_k<<<(NA+255)/256, 256, 0, stream>>>(attrs, ae, h2, Wread, batch, out_e);

  // backward
  pb_bwd_k<<<(NA*KC+255)/256, 256, 0, stream>>>(A2, Wp + 384, (const float*)nullptr, Wread, 1, gA);
  bwd_edge_k<<<NE/ECH, 256, 0, stream>>>(eidx, shb, rbb, vecb, rbuf, hu2, Wr1 + 512, Wr2 + 65536, Wr2T + 65536, gA, ghu2, 1, gpos);
  ghu_to_gh_k<<<(NA*KC+255)/256, 256, 0, stream>>>(ghu2, lin + 4096, gh1);
  pb_bwd_k<<<(NA*KC+255)/256, 256, 0, stream>>>(A1, Wp + 0, gh1, (const float*)nullptr, 0, gA);
  bwd_edge_k<<<NE/ECH, 256, 0, stream>>>(eidx, shb, rbb, vecb, rbuf, hu1, Wr1 + 0, Wr2 + 0, Wr2T + 0, gA, (float*)nullptr, 0, gpos);

  forces_k<<<(NA*3+255)/256, 256, 0, stream>>>(gpos, out_f);
}

// Round 3
// 1864.356 us; speedup vs baseline: 1.7208x; 1.7208x over previous
//
#include <hip/hip_runtime.h>
#include <cmath>
#include <type_traits>
#include <utility>

#define NA 10000
#define NE 160000
#define KC 64
#define NEL 10
#define NBR 8
#define NGR 16
#define ECH 16

#define C0 0.28209479177387814f
#define C1 0.4886025119029199f
#define C2 1.0925484305920792f
#define C3 0.31539156525252005f
#define C4 0.5462742152960396f
#define C5 0.5900435899266435f
#define C6 2.890611442640554f
#define C7 0.4570457994644658f
#define C8 0.3731763325901154f
#define C9 1.445305721320277f
#define SQ4PI 3.5449077018110318f
#define PREF 0.6324555320336759f   // sqrt(2/5)
#define PI_F 3.14159265358979323846f

typedef float f32x4 __attribute__((ext_vector_type(4)));
typedef short s16x8 __attribute__((ext_vector_type(8)));
typedef __bf16 b16x8 __attribute__((ext_vector_type(8)));

__device__ __forceinline__ float sigmoidf_(float x){ return 1.0f/(1.0f+expf(-x)); }

__device__ __forceinline__ unsigned short f2b(float f){
  unsigned int u = __float_as_uint(f);
  unsigned int r = u + 0x7FFFu + ((u>>16)&1u);
  return (unsigned short)(r>>16);
}

// SFINAE wrapper: handles both possible builtin signatures (short8 or bf16x8)
template<typename T, typename = void>
struct mfma_takes_short : std::false_type {};
template<typename T>
struct mfma_takes_short<T, std::void_t<decltype(__builtin_amdgcn_mfma_f32_16x16x32_bf16(
    std::declval<T>(), std::declval<T>(), std::declval<f32x4>(), 0, 0, 0))>> : std::true_type {};

__device__ __forceinline__ f32x4 mfma16(s16x8 a, s16x8 b, f32x4 c){
  if constexpr (mfma_takes_short<s16x8>::value)
    return __builtin_amdgcn_mfma_f32_16x16x32_bf16(a, b, c, 0, 0, 0);
  else
    return __builtin_amdgcn_mfma_f32_16x16x32_bf16(
        __builtin_bit_cast(b16x8, a), __builtin_bit_cast(b16x8, b), c, 0, 0, 0);
}

// ---------------- edge geometry ----------------
__global__ void edge_geom_k(const float* __restrict__ pos, const float* __restrict__ shifts,
                            const int* __restrict__ eidx,
                            float* __restrict__ vecb, float* __restrict__ rbuf,
                            float* __restrict__ shb, float* __restrict__ rbb){
  int e = blockIdx.x*blockDim.x + threadIdx.x;
  if (e >= NE) return;
  int sn = eidx[e], rc = eidx[NE+e];
  float vx = pos[rc*3+0]-pos[sn*3+0]+shifts[e*3+0];
  float vy = pos[rc*3+1]-pos[sn*3+1]+shifts[e*3+1];
  float vz = pos[rc*3+2]-pos[sn*3+2]+shifts[e*3+2];
  float r = sqrtf(vx*vx+vy*vy+vz*vz+1e-12f);
  vecb[e*3+0]=vx; vecb[e*3+1]=vy; vecb[e*3+2]=vz; rbuf[e]=r;
  float inv = 1.0f/r; float x=vx*inv,y=vy*inv,z=vz*inv;
  float x2=x*x,y2=y*y,z2=z*z;
  float Y[16];
  Y[0]=C0; Y[1]=C1*y; Y[2]=C1*z; Y[3]=C1*x;
  Y[4]=C2*x*y; Y[5]=C2*y*z; Y[6]=C3*(3.f*z2-1.f); Y[7]=C2*x*z; Y[8]=C4*(x2-y2);
  Y[9]=C5*y*(3.f*x2-y2); Y[10]=C6*x*y*z; Y[11]=C7*y*(5.f*z2-1.f);
  Y[12]=C8*z*(5.f*z2-3.f); Y[13]=C7*x*(5.f*z2-1.f); Y[14]=C9*z*(x2-y2);
  Y[15]=C5*x*(x2-3.f*y2);
  #pragma unroll
  for (int m=0;m<16;m++) shb[e*16+m] = Y[m]*SQ4PI;
  float u = r*0.2f;
  float fc = 0.f;
  if (u < 1.0f){ float u2=u*u,u4=u2*u2,u5=u4*u,u6=u5*u,u7=u6*u; fc = 1.f-21.f*u5+35.f*u6-15.f*u7; }
  #pragma unroll
  for (int b=0;b<NBR;b++){
    float a = (float)(b+1)*PI_F*0.2f;
    rbb[e*NBR+b] = PREF*sinf(a*r)*inv*fc;
  }
}

// ---------------- embed ----------------
__global__ void embed_k(const float* __restrict__ attrs, const float* __restrict__ W, float* __restrict__ h0){
  int idx = blockIdx.x*blockDim.x+threadIdx.x;
  if (idx >= NA*KC) return;
  int n = idx>>6, k = idx&63;
  float s=0;
  #pragma unroll
  for (int j=0;j<NEL;j++) s += attrs[n*NEL+j]*W[j*KC+k];
  h0[idx]=s;
}

__global__ void hu_k(const float* __restrict__ h, const float* __restrict__ lin, float* __restrict__ out){
  int idx = blockIdx.x*blockDim.x+threadIdx.x;
  if (idx >= NA*KC) return;
  int n = idx>>6, k = idx&63;
  float s=0;
  for (int c=0;c<KC;c++) s += h[n*KC+c]*lin[c*KC+k];
  out[idx]=s;
}

__global__ void ghu_to_gh_k(const float* __restrict__ g, const float* __restrict__ lin, float* __restrict__ out){
  int idx = blockIdx.x*blockDim.x+threadIdx.x;
  if (idx >= NA*KC) return;
  int n = idx>>6, k = idx&63;
  float s=0;
  for (int c=0;c<KC;c++) s += g[n*KC+c]*lin[k*KC+c];
  out[idx]=s;
}

// ---------------- CSR build ----------------
__global__ void count_k(const int* __restrict__ eidx, int* __restrict__ cnt){
  int e = blockIdx.x*blockDim.x+threadIdx.x;
  if (e<NE) atomicAdd(&cnt[eidx[NE+e]], 1);
}
__global__ void scan_k(const int* __restrict__ cnt, int* __restrict__ rs, int* __restrict__ fill){
  __shared__ int part[256];
  int t = threadIdx.x;
  const int PER = (NA + 255)/256;
  int base = t*PER;
  int s = 0;
  for (int j=0;j<PER;j++){ int i=base+j; if (i<NA) s += cnt[i]; }
  part[t] = s; __syncthreads();
  for (int off=1; off<256; off<<=1){
    int v = (t>=off) ? part[t-off] : 0;
    __syncthreads();
    part[t] += v;
    __syncthreads();
  }
  int run = (t==0) ? 0 : part[t-1];
  for (int j=0;j<PER;j++){ int i=base+j; if (i<NA){ rs[i]=run; fill[i]=run; run += cnt[i]; } }
  if (t==255) rs[NA]=run;
}
__global__ void place_k(const int* __restrict__ eidx, int* __restrict__ fill, int* __restrict__ perm){
  int e = blockIdx.x*blockDim.x+threadIdx.x;
  if (e>=NE) return;
  int r = eidx[NE+e];
  int p = atomicAdd(&fill[r],1);
  perm[p]=e;
}

// ---------------- weight prep: bf16 copies of Wr2 ([c][o]) and Wr2^T ([o][c]) ----------------
__global__ void prep_w_k(const float* __restrict__ Wr2, unsigned short* __restrict__ w2b,
                         unsigned short* __restrict__ w2t){
  int idx = blockIdx.x*blockDim.x+threadIdx.x;
  if (idx >= 2*65536) return;
  int l = idx>>16;
  int rem = idx & 65535;
  int c = rem>>10, o = rem&1023;
  unsigned short v = f2b(Wr2[idx]);
  w2b[idx] = v;
  w2t[l*65536 + o*64 + c] = v;
}

// ---------------- forward: A accumulation per node (MFMA) ----------------
__global__ __launch_bounds__(256) void fwd_A_k(const int* __restrict__ rs, const int* __restrict__ perm,
    const int* __restrict__ eidx, const float* __restrict__ shb, const float* __restrict__ rbb,
    const float* __restrict__ hu, const float* __restrict__ Wr1, const unsigned short* __restrict__ w2t,
    float* __restrict__ A){
  __shared__ __align__(16) unsigned short s_s[16*64];   // bf16, XOR-swizzled
  __shared__ float s_sh[16*17];
  __shared__ float s_hu[16*68];
  __shared__ float s_rb[16*8];
  __shared__ float s_w1[8*64];
  __shared__ int s_snd[16];
  int n = blockIdx.x, t = threadIdx.x;
  int lane = t & 63, w = t >> 6;
  int row = lane & 15, g = lane >> 4;
  int e0 = rs[n], e1 = rs[n+1];
  s_w1[t] = Wr1[t]; s_w1[256+t] = Wr1[256+t];
  float acc[16];
  #pragma unroll
  for (int i=0;i<16;i++) acc[i]=0.f;

  for (int ce=e0; ce<e1; ce+=ECH){
    int ne = min(ECH, e1-ce);
    __syncthreads();
    if (t<ECH) s_snd[t] = (t<ne) ? eidx[perm[ce+t]] : -1;
    { int le=t>>4, m=t&15; s_sh[le*17+m] = (le<ne) ? shb[perm[ce+le]*16+m] : 0.f; }
    if (t < ECH*NBR){ int le=t>>3, b=t&7; s_rb[le*8+b] = (le<ne) ? rbb[perm[ce+le]*NBR+b] : 0.f; }
    __syncthreads();
    #pragma unroll
    for (int q=0;q<4;q++){
      int idx=q*256+t; int le=idx>>6, c=idx&63;
      int sn = s_snd[le];
      s_hu[le*68+c] = (sn>=0) ? hu[sn*KC+c] : 0.f;
      float tt=0;
      #pragma unroll
      for (int b=0;b<NBR;b++) tt += s_rb[le*8+b]*s_w1[b*64+c];
      float sv = tt*sigmoidf_(tt);
      s_s[le*64 + (c ^ ((le&7)<<3))] = (sn>=0) ? f2b(sv) : (unsigned short)0;
    }
    __syncthreads();
    s16x8 a0 = *(const s16x8*)&s_s[row*64 + ((g*8)      ^ ((row&7)<<3))];
    s16x8 a1 = *(const s16x8*)&s_s[row*64 + ((32 + g*8) ^ ((row&7)<<3))];
    #pragma unroll 4
    for (int ot=0; ot<16; ot++){
      int otile = w*16 + ot;
      const unsigned short* bp = w2t + (otile*16 + row)*64 + g*8;
      s16x8 b0 = *(const s16x8*)(bp);
      s16x8 b1 = *(const s16x8*)(bp + 32);
      f32x4 d = {0.f,0.f,0.f,0.f};
      d = mfma16(a0, b0, d);
      d = mfma16(a1, b1, d);
      float s = 0.f;
      #pragma unroll
      for (int q=0;q<4;q++){
        int e = g*4+q;
        s += d[q] * s_sh[e*17+row] * s_hu[e*68+otile];
      }
      acc[ot] += s;
    }
  }
  const float inv16 = 1.f/16.f;
  #pragma unroll
  for (int ot=0; ot<16; ot++){
    float v = acc[ot];
    v += __shfl_xor(v, 16);
    v += __shfl_xor(v, 32);
    if (lane < 16) A[n*1024 + (w*16+ot)*16 + lane] = v*inv16;
  }
}

// ---------------- product basis fwd ----------------
__global__ void pb_fwd_k(const float* __restrict__ A, const float* __restrict__ Wp, float* __restrict__ h){
  int idx = blockIdx.x*blockDim.x+threadIdx.x;
  if (idx>=NA*KC) return;
  int k = idx&63;
  const float* a = A + idx*16;
  float v[16];
  #pragma unroll
  for (int m=0;m<16;m++) v[m]=a[m];
  float p0 = v[0]*v[0];
  float p1 = v[1]*v[1]+v[2]*v[2]+v[3]*v[3];
  float p2 = v[4]*v[4]+v[5]*v[5]+v[6]*v[6]+v[7]*v[7]+v[8]*v[8];
  float p3 = 0.f;
  #pragma unroll
  for (int m=9;m<16;m++) p3 += v[m]*v[m];
  float P = p0+p1+p2+p3;
  const float* wp = Wp + k*6;
  h[idx] = v[0]*wp[0] + p0*wp[1] + p1*wp[2] + p2*wp[3] + p3*wp[4] + v[0]*P*wp[5];
}

// ---------------- product basis bwd ----------------
__global__ void pb_bwd_k(const float* __restrict__ A, const float* __restrict__ Wp,
                         const float* __restrict__ gh, const float* __restrict__ Wread,
                         int useW, float* __restrict__ gA){
  int idx = blockIdx.x*blockDim.x+threadIdx.x;
  if (idx>=NA*KC) return;
  int k = idx&63;
  const float* a = A + idx*16;
  float v[16];
  #pragma unroll
  for (int m=0;m<16;m++) v[m]=a[m];
  float p0 = v[0]*v[0];
  float p1 = v[1]*v[1]+v[2]*v[2]+v[3]*v[3];
  float p2 = v[4]*v[4]+v[5]*v[5]+v[6]*v[6]+v[7]*v[7]+v[8]*v[8];
  float p3 = 0.f;
  #pragma unroll
  for (int m=9;m<16;m++) p3 += v[m]*v[m];
  float P = p0+p1+p2+p3;
  float g = useW ? Wread[k] : gh[idx];
  const float* wp = Wp + k*6;
  float w5a0 = wp[5]*v[0];
  float out[16];
  #pragma unroll
  for (int m=0;m<16;m++){
    int l = (m==0)?0:(m<4)?1:(m<9)?2:3;
    float r = 2.f*v[m]*(wp[1+l] + w5a0);
    if (m==0) r += wp[0] + wp[5]*P;
    out[m] = g*r;
  }
  float* d = gA + idx*16;
  #pragma unroll
  for (int m=0;m<16;m++) d[m]=out[m];
}

// ---------------- backward edge kernel (MFMA) ----------------
__global__ __launch_bounds__(256) void bwd_edge_k(const int* __restrict__ eidx,
    const float* __restrict__ shb, const float* __restrict__ rbb,
    const float* __restrict__ vecb, const float* __restrict__ rbuf,
    const float* __restrict__ hu, const float* __restrict__ Wr1,
    const unsigned short* __restrict__ w2b,   // Wr2 bf16 [c][o]
    const unsigned short* __restrict__ w2t,   // Wr2^T bf16 [o][c]
    const float* __restrict__ gA, float* __restrict__ ghu, int do_ghu,
    float* __restrict__ gpos){
  __shared__ __align__(16) unsigned short s_s[16*64];      // bf16 swizzled
  __shared__ __align__(16) unsigned short s_gR[16*1024];   // 32 KB bf16 swizzled
  __shared__ float s_sh[16*17];
  __shared__ float s_hu[16*68];
  __shared__ float s_rb[16*8];
  __shared__ float s_w1[8*64];
  __shared__ float s_gshp[4*16*17];
  __shared__ float s_gt[16*64];
  __shared__ float s_grb[16*8];
  __shared__ int s_snd[16], s_rcv[16];
  int t = threadIdx.x, lane = t&63, w = t>>6;
  int row = lane&15, g = lane>>4;
  int eb = blockIdx.x*ECH;
  const float inv16 = 1.f/16.f;

  s_w1[t] = Wr1[t]; s_w1[256+t] = Wr1[256+t];
  if (t<ECH){ s_snd[t]=eidx[eb+t]; s_rcv[t]=eidx[NE+eb+t]; }
  { int le=t>>4, m=t&15; s_sh[le*17+m]=shb[(eb+le)*16+m]; }
  if (t<ECH*NBR){ int le=t>>3, b=t&7; s_rb[le*8+b]=rbb[(eb+le)*NBR+b]; }
  __syncthreads();
  #pragma unroll
  for (int q=0;q<4;q++){
    int idx=q*256+t; int le=idx>>6, c=idx&63;
    s_hu[le*68+c]=hu[s_snd[le]*KC+c];
    float tt=0;
    #pragma unroll
    for (int b=0;b<NBR;b++) tt += s_rb[le*8+b]*s_w1[b*64+c];
    s_s[le*64 + (c ^ ((le&7)<<3))] = f2b(tt*sigmoidf_(tt));
  }
  __syncthreads();

  // ---- Phase 1: recompute R via MFMA; fuse g_hu / g_sh / gR formation ----
  s16x8 a0 = *(const s16x8*)&s_s[row*64 + ((g*8)      ^ ((row&7)<<3))];
  s16x8 a1 = *(const s16x8*)&s_s[row*64 + ((32 + g*8) ^ ((row&7)<<3))];
  float gsh_acc[4] = {0.f,0.f,0.f,0.f};
  #pragma unroll 2
  for (int ot=0; ot<16; ot++){
    int k = w*16 + ot;   // otile == k
    const unsigned short* bp = w2t + (k*16 + row)*64 + g*8;
    s16x8 b0 = *(const s16x8*)(bp);
    s16x8 b1 = *(const s16x8*)(bp + 32);
    f32x4 d = {0.f,0.f,0.f,0.f};
    d = mfma16(a0, b0, d);
    d = mfma16(a1, b1, d);
    float gm[4], ghv[4];
    #pragma unroll
    for (int q=0;q<4;q++) gm[q] = gA[s_rcv[g*4+q]*1024 + k*16 + row]*inv16;
    #pragma unroll
    for (int q=0;q<4;q++){
      int e = g*4+q;
      float shv = s_sh[e*17+row];
      float huv = s_hu[e*68+k];
      float p = gm[q]*d[q];         // gmsg * R
      ghv[q] = p*shv;               // -> g_hu
      gsh_acc[q] += p*huv;          // -> g_sh
      float gr = gm[q]*shv*huv;     // g_R
      s_gR[e*1024 + ((k*16+row) ^ ((e&7)<<3))] = f2b(gr);
    }
    if (do_ghu){
      #pragma unroll
      for (int off=1; off<16; off<<=1){
        ghv[0]+=__shfl_xor(ghv[0],off); ghv[1]+=__shfl_xor(ghv[1],off);
        ghv[2]+=__shfl_xor(ghv[2],off); ghv[3]+=__shfl_xor(ghv[3],off);
      }
      if (row==0){
        #pragma unroll
        for (int q=0;q<4;q++) atomicAdd(&ghu[s_snd[g*4+q]*KC + k], ghv[q]);
      }
    }
  }
  #pragma unroll
  for (int q=0;q<4;q++) s_gshp[w*272 + (g*4+q)*17 + row] = gsh_acc[q];
  __syncthreads();

  // ---- Phase 2: g_s = gR @ Wr2^T (K=1024), wave w owns c-tile w ----
  f32x4 dgs = {0.f,0.f,0.f,0.f};
  #pragma unroll 4
  for (int kb=0; kb<32; kb++){
    int kelem = kb*32 + g*8;
    s16x8 a = *(const s16x8*)&s_gR[row*1024 + (kelem ^ ((row&7)<<3))];
    s16x8 b = *(const s16x8*)&w2b[(w*16+row)*1024 + kelem];
    dgs = mfma16(a, b, dgs);
  }
  // g_t = g_s * dsilu(tt)
  #pragma unroll
  for (int q=0;q<4;q++){
    int e = g*4+q, c = w*16+row;
    float tt=0;
    #pragma unroll
    for (int b=0;b<NBR;b++) tt += s_rb[e*8+b]*s_w1[b*64+c];
    float sg = sigmoidf_(tt);
    float ds = sg*(1.f+tt*(1.f-sg));
    s_gt[e*64 + c] = dgs[q]*ds;
  }
  __syncthreads();

  // g_rb
  if (t < ECH*NBR){
    int le=t>>3, b=t&7;
    float s=0;
    for (int c=0;c<KC;c++) s += s_gt[le*64+c]*s_w1[b*64+c];
    s_grb[le*8+b]=s;
  }
  // reduce gsh partials
  { int le=t>>4, m=t&15;
    s_gshp[le*17+m] = s_gshp[le*17+m]+s_gshp[272+le*17+m]+s_gshp[544+le*17+m]+s_gshp[816+le*17+m]; }
  __syncthreads();

  // per-edge geometry backward
  if (t < ECH){
    int le=t; int e=eb+le;
    float r = rbuf[e]; float inv=1.f/r;
    float vx=vecb[e*3+0], vy=vecb[e*3+1], vz=vecb[e*3+2];
    float x=vx*inv, y=vy*inv, z=vz*inv;
    float x2=x*x, y2=y*y, z2=z*z;
    float G[16];
    #pragma unroll
    for (int m=0;m<16;m++) G[m]=s_gshp[le*17+m];
    float gx = C1*G[3] + C2*(y*G[4]+z*G[7]) + 2.f*C4*x*G[8] + 6.f*C5*x*y*G[9]
             + C6*y*z*G[10] + C7*(5.f*z2-1.f)*G[13] + 2.f*C9*x*z*G[14] + 3.f*C5*(x2-y2)*G[15];
    float gy = C1*G[1] + C2*(x*G[4]+z*G[5]) - 2.f*C4*y*G[8] + 3.f*C5*(x2-y2)*G[9]
             + C6*x*z*G[10] + C7*(5.f*z2-1.f)*G[11] - 2.f*C9*y*z*G[14] - 6.f*C5*x*y*G[15];
    float gz = C1*G[2] + C2*(y*G[5]+x*G[7]) + 6.f*C3*z*G[6] + C6*x*y*G[10]
             + 10.f*C7*y*z*G[11] + C8*(15.f*z2-3.f)*G[12] + 10.f*C7*x*z*G[13] + C9*(x2-y2)*G[14];
    gx*=SQ4PI; gy*=SQ4PI; gz*=SQ4PI;
    float gr=0.f;
    float u=r*0.2f;
    if (u<1.f){
      float u2=u*u, u4=u2*u2, u5=u4*u, u6=u5*u, u7=u6*u;
      float fc=1.f-21.f*u5+35.f*u6-15.f*u7;
      float dfc=(-105.f*u4+210.f*u5-105.f*u6)*0.2f;
      #pragma unroll
      for (int b=0;b<NBR;b++){
        float a=(float)(b+1)*PI_F*0.2f;
        float sa=sinf(a*r), ca=cosf(a*r);
        float bes=PREF*sa*inv;
        float dbes=PREF*(a*ca*inv - sa*inv*inv);
        gr += s_grb[le*8+b]*(dbes*fc + bes*dfc);
      }
    }
    float dot = x*gx+y*gy+z*gz;
    float gvx = (gx - x*dot)*inv + gr*x;
    float gvy = (gy - y*dot)*inv + gr*y;
    float gvz = (gz - z*dot)*inv + gr*z;
    int sn=s_snd[le], rc=s_rcv[le];
    atomicAdd(&gpos[rc*3+0], gvx); atomicAdd(&gpos[rc*3+1], gvy); atomicAdd(&gpos[rc*3+2], gvz);
    atomicAdd(&gpos[sn*3+0], -gvx); atomicAdd(&gpos[sn*3+1], -gvy); atomicAdd(&gpos[sn*3+2], -gvz);
  }
}

// ---------------- energy + forces ----------------
__global__ void energy_k(const float* __restrict__ attrs, const float* __restrict__ ae,
                         const float* __restrict__ h2, const float* __restrict__ Wread,
                         const int* __restrict__ batch, float* __restrict__ out_e){
  int n = blockIdx.x*blockDim.x+threadIdx.x;
  if (n>=NA) return;
  float v=0;
  #pragma unroll
  for (int j=0;j<NEL;j++) v += attrs[n*NEL+j]*ae[j];
  float s=0;
  for (int kk=0;kk<KC;kk++) s += h2[n*KC+kk]*Wread[kk];
  atomicAdd(&out_e[batch[n]], v+s);
}
__global__ void forces_k(const float* __restrict__ gpos, float* __restrict__ out_f){
  int i = blockIdx.x*blockDim.x+threadIdx.x;
  if (i<NA*3) out_f[i] = -gpos[i];
}

extern "C" void kernel_launch(void* const* d_in, const int* in_sizes, int n_in,
                              void* d_out, int out_size, void* d_ws, size_t ws_size,
                              hipStream_t stream){
  const float* pos    = (const float*)d_in[0];
  const float* attrs  = (const float*)d_in[1];
  const float* shifts = (const float*)d_in[2];
  const int*   eidx   = (const int*)d_in[3];
  const int*   batch  = (const int*)d_in[4];
  const float* ae     = (const float*)d_in[6];
  const float* embedW = (const float*)d_in[7];
  const float* Wr1    = (const float*)d_in[8];
  const float* Wr2    = (const float*)d_in[9];
  const float* lin    = (const float*)d_in[10];
  const float* Wp     = (const float*)d_in[11];
  const float* Wread  = (const float*)d_in[12];
  float* out_e = (float*)d_out;
  float* out_f = out_e + NGR;

  char* w = (char*)d_ws;
  auto alloc = [&](size_t nElem)->void*{ void* p = (void*)w; w += ((nElem*4 + 255)/256)*256; return p; };
  float* vecb = (float*)alloc((size_t)3*NE);
  float* rbuf = (float*)alloc((size_t)NE);
  float* shb  = (float*)alloc((size_t)16*NE);
  float* rbb  = (float*)alloc((size_t)8*NE);
  float* h0   = (float*)alloc((size_t)NA*KC);
  float* h1   = (float*)alloc((size_t)NA*KC);
  float* h2   = (float*)alloc((size_t)NA*KC);
  float* hu1  = (float*)alloc((size_t)NA*KC);
  float* hu2  = (float*)alloc((size_t)NA*KC);
  float* gh1  = (float*)alloc((size_t)NA*KC);
  float* ghu2 = (float*)alloc((size_t)NA*KC);
  float* A1   = (float*)alloc((size_t)NA*1024);
  float* A2   = (float*)alloc((size_t)NA*1024);
  float* gA   = (float*)alloc((size_t)NA*1024);
  float* gpos = (float*)alloc((size_t)NA*3);
  unsigned short* w2b = (unsigned short*)alloc((size_t)2*65536);  // bf16, overalloc'd x2
  unsigned short* w2t = (unsigned short*)alloc((size_t)2*65536);
  int* cnt  = (int*)alloc((size_t)NA);
  int* rsar = (int*)alloc((size_t)NA+1);
  int* fill = (int*)alloc((size_t)NA);
  int* perm = (int*)alloc((size_t)NE);

  hipMemsetAsync(cnt, 0, NA*sizeof(int), stream);
  hipMemsetAsync(gpos, 0, NA*3*sizeof(float), stream);
  hipMemsetAsync(ghu2, 0, NA*KC*sizeof(float), stream);
  hipMemsetAsync(out_e, 0, NGR*sizeof(float), stream);

  prep_w_k<<<(2*65536+255)/256, 256, 0, stream>>>(Wr2, w2b, w2t);
  edge_geom_k<<<(NE+255)/256, 256, 0, stream>>>(pos, shifts, eidx, vecb, rbuf, shb, rbb);
  embed_k<<<(NA*KC+255)/256, 256, 0, stream>>>(attrs, embedW, h0);
  count_k<<<(NE+255)/256, 256, 0, stream>>>(eidx, cnt);
  scan_k<<<1, 256, 0, stream>>>(cnt, rsar, fill);
  place_k<<<(NE+255)/256, 256, 0, stream>>>(eidx, fill, perm);

  // layer 0
  hu_k<<<(NA*KC+255)/256, 256, 0, stream>>>(h0, lin + 0, hu1);
  fwd_A_k<<<NA, 256, 0, stream>>>(rsar, perm, eidx, shb, rbb, hu1, Wr1 + 0, w2t + 0, A1);
  pb_fwd_k<<<(NA*KC+255)/256, 256, 0, stream>>>(A1, Wp + 0, h1);
  // layer 1
  hu_k<<<(NA*KC+255)/256, 256, 0, stream>>>(h1, lin + 4096, hu2);
  fwd_A_k<<<NA, 256, 0, stream>>>(rsar, perm, eidx, shb, rbb, hu2, Wr1 + 512, w2t + 65536, A2);
  pb_fwd_k<<<(NA*KC+255)/256, 256, 0, stream>>>(A2, Wp + 384, h2);

  energy_k<<<(NA+255)/256, 256, 0, stream>>>(attrs, ae, h2, Wread, batch, out_e);

  // backward
  pb_bwd_k<<<(NA*KC+255)/256, 256, 0, stream>>>(A2, Wp + 384, (const float*)nullptr, Wread, 1, gA);
  bwd_edge_k<<<NE/ECH, 256, 0, stream>>>(eidx, shb, rbb, vecb, rbuf, hu2, Wr1 + 512, w2b + 65536, w2t + 65536, gA, ghu2, 1, gpos);
  ghu_to_gh_k<<<(NA*KC+255)/256, 256, 0, stream>>>(ghu2, lin + 4096, gh1);
  pb_bwd_k<<<(NA*KC+255)/256, 256, 0, stream>>>(A1, Wp + 0, gh1, (const float*)nullptr, 0, gA);
  bwd_edge_k<<<NE/ECH, 256, 0, stream>>>(eidx, shb, rbb, vecb, rbuf, hu1, Wr1 + 0, w2b + 0, w2t + 0, gA, (float*)nullptr, 0, gpos);

  forces_k<<<(NA*3+255)/256, 256, 0, stream>>>(gpos, out_f);
}